// Round 1
// baseline (689.906 us; speedup 1.0000x reference)
//
#include <hip/hip_runtime.h>
#include <math.h>
#include <stddef.h>

#define D_DIM 128
#define NUM_RBF 20
constexpr float PI_F = 3.14159265358979323846f;
constexpr float CUT_OFF_F = 5.0f;
constexpr float SILU_SCALE_F = 1.0f / 0.6f;

// ---------------------------------------------------------------------------
// Fused node projection: s = scaled_silu(X @ W1 + b1) @ W2 + b2   [N, 384]
// Block: 256 threads, 32 rows per block. 4x4 register tile per thread.
// LDS: region A (16KB) = X tile, then reused for h. region B (64KB) = W1,
// then reused for W2 K-chunks (48KB).
// ---------------------------------------------------------------------------
__global__ __launch_bounds__(256) void proj_kernel(
    const float* __restrict__ X, const float* __restrict__ W1,
    const float* __restrict__ b1, const float* __restrict__ W2,
    const float* __restrict__ b2, float* __restrict__ s_out, int N) {
  __shared__ float smA[32 * 128];    // xs then hs
  __shared__ float smB[128 * 128];   // W1 then W2 chunk
  float* xs = smA;
  float* hs = smA;
  float* w1s = smB;
  float* w2c = smB;

  const int t = threadIdx.x;
  const int nb = blockIdx.x * 32;

  // ---- load X tile (32 rows x 128) ----
  {
    const float4* Xv = reinterpret_cast<const float4*>(X);
    float4* xsv = reinterpret_cast<float4*>(xs);
#pragma unroll
    for (int i = 0; i < 4; ++i) {
      int f4 = t + i * 256;          // 0..1023, 32 float4 per row
      int node = nb + (f4 >> 5);
      xsv[f4] = (node < N) ? Xv[(size_t)nb * 32 + f4]
                           : make_float4(0.f, 0.f, 0.f, 0.f);
    }
  }
  // ---- load W1 (128x128) ----
  {
    const float4* W1v = reinterpret_cast<const float4*>(W1);
    float4* wv = reinterpret_cast<float4*>(w1s);
#pragma unroll
    for (int i = 0; i < 16; ++i) wv[t + i * 256] = W1v[t + i * 256];
  }
  __syncthreads();

  const int c0 = (t & 31) * 4;   // col 0..124
  const int r0 = (t >> 5) * 4;   // row 0..28

  // ---- phase 1: h = X @ W1 ----
  float acc1[4][4] = {};
  for (int k = 0; k < 128; k += 4) {
    float xa[4][4];
#pragma unroll
    for (int i = 0; i < 4; ++i) {
      float4 xt = *reinterpret_cast<const float4*>(&xs[(r0 + i) * 128 + k]);
      xa[i][0] = xt.x; xa[i][1] = xt.y; xa[i][2] = xt.z; xa[i][3] = xt.w;
    }
#pragma unroll
    for (int kk = 0; kk < 4; ++kk) {
      float4 wv = *reinterpret_cast<const float4*>(&w1s[(k + kk) * 128 + c0]);
      float wa[4] = {wv.x, wv.y, wv.z, wv.w};
#pragma unroll
      for (int i = 0; i < 4; ++i)
#pragma unroll
        for (int j = 0; j < 4; ++j) acc1[i][j] += xa[i][kk] * wa[j];
    }
  }
  __syncthreads();   // xs reads complete before hs overwrite

  // ---- bias + scaled silu, store h to LDS ----
  {
    float b1v[4];
#pragma unroll
    for (int j = 0; j < 4; ++j) b1v[j] = b1[c0 + j];
#pragma unroll
    for (int i = 0; i < 4; ++i) {
#pragma unroll
      for (int j = 0; j < 4; ++j) {
        float h = acc1[i][j] + b1v[j];
        h = h * SILU_SCALE_F / (1.0f + expf(-h));
        hs[(r0 + i) * 128 + c0 + j] = h;
      }
    }
  }

  // ---- phase 2: s = h @ W2 + b2, K in 4 chunks of 32 ----
  float acc2[4][3][4];
#pragma unroll
  for (int m = 0; m < 3; ++m)
#pragma unroll
    for (int j = 0; j < 4; ++j) {
      float bv = b2[m * 128 + c0 + j];
#pragma unroll
      for (int i = 0; i < 4; ++i) acc2[i][m][j] = bv;
    }

  for (int kc = 0; kc < 128; kc += 32) {
    __syncthreads();   // prev chunk reads done / hs writes visible
    {
      const float4* W2v = reinterpret_cast<const float4*>(W2);
      float4* wv = reinterpret_cast<float4*>(w2c);
#pragma unroll
      for (int i = 0; i < 12; ++i)
        wv[t + i * 256] = W2v[(size_t)kc * 96 + t + i * 256];
    }
    __syncthreads();
    for (int kk = 0; kk < 32; ++kk) {
      float xr[4];
#pragma unroll
      for (int i = 0; i < 4; ++i) xr[i] = hs[(r0 + i) * 128 + kc + kk];
#pragma unroll
      for (int m = 0; m < 3; ++m) {
        float4 wv = *reinterpret_cast<const float4*>(&w2c[kk * 384 + m * 128 + c0]);
        float wa[4] = {wv.x, wv.y, wv.z, wv.w};
#pragma unroll
        for (int i = 0; i < 4; ++i)
#pragma unroll
          for (int j = 0; j < 4; ++j) acc2[i][m][j] += xr[i] * wa[j];
      }
    }
  }

  // ---- store s ----
#pragma unroll
  for (int i = 0; i < 4; ++i) {
    int node = nb + r0 + i;
    if (node < N) {
#pragma unroll
      for (int m = 0; m < 3; ++m) {
        float4 v = make_float4(acc2[i][m][0], acc2[i][m][1], acc2[i][m][2],
                               acc2[i][m][3]);
        *reinterpret_cast<float4*>(&s_out[(size_t)node * 384 + m * 128 + c0]) = v;
      }
    }
  }
}

// ---------------------------------------------------------------------------
// CSR build
// ---------------------------------------------------------------------------
__global__ void zero_kernel(int* __restrict__ p, int n) {
  int i = blockIdx.x * 256 + threadIdx.x;
  if (i < n) p[i] = 0;
}

__global__ void hist_kernel(const int* __restrict__ tgt, int* __restrict__ counts,
                            int E) {
  int e = blockIdx.x * 256 + threadIdx.x;
  if (e < E) atomicAdd(&counts[tgt[e]], 1);
}

__global__ void chunk_sum_kernel(const int* __restrict__ counts,
                                 int* __restrict__ chunk_sums, int N) {
  __shared__ int red[256];
  int b = blockIdx.x, t = threadIdx.x;
  int base = b * 1024 + t * 4;
  int s = 0;
#pragma unroll
  for (int j = 0; j < 4; ++j) s += (base + j < N) ? counts[base + j] : 0;
  red[t] = s;
  __syncthreads();
  for (int off = 128; off > 0; off >>= 1) {
    if (t < off) red[t] += red[t + off];
    __syncthreads();
  }
  if (t == 0) chunk_sums[b] = red[0];
}

__global__ void scan_chunks_kernel(int* __restrict__ chunk_sums,
                                   int* __restrict__ offsets, int nch, int N,
                                   int E) {
  int t = threadIdx.x;  // 64 threads, one wave; nch <= 64
  int v = (t < nch) ? chunk_sums[t] : 0;
  int orig = v;
#pragma unroll
  for (int off = 1; off < 64; off <<= 1) {
    int y = __shfl_up(v, off);
    if (t >= off) v += y;
  }
  if (t < nch) chunk_sums[t] = v - orig;  // exclusive prefix
  if (t == 0) offsets[N] = E;
}

__global__ void scan_block_kernel(const int* __restrict__ counts,
                                  const int* __restrict__ chunk_off,
                                  int* __restrict__ offsets,
                                  int* __restrict__ cursor, int N) {
  __shared__ int part[256];
  int b = blockIdx.x, t = threadIdx.x;
  int base = b * 1024 + t * 4;
  int v[4];
#pragma unroll
  for (int j = 0; j < 4; ++j) v[j] = (base + j < N) ? counts[base + j] : 0;
  int local = v[0] + v[1] + v[2] + v[3];
  part[t] = local;
  __syncthreads();
  for (int off = 1; off < 256; off <<= 1) {
    int x = 0;
    if (t >= off) x = part[t - off];
    __syncthreads();
    if (t >= off) part[t] += x;
    __syncthreads();
  }
  int run = chunk_off[b] + (part[t] - local);
#pragma unroll
  for (int j = 0; j < 4; ++j) {
    if (base + j < N) {
      offsets[base + j] = run;
      cursor[base + j] = run;
      run += v[j];
    }
  }
}

__global__ void fill_kernel(const int* __restrict__ tgt, int* __restrict__ cursor,
                            int* __restrict__ edge_ord, int E) {
  int e = blockIdx.x * 256 + threadIdx.x;
  if (e < E) {
    int p = atomicAdd(&cursor[tgt[e]], 1);
    edge_ord[p] = e;
  }
}

// ---------------------------------------------------------------------------
// Node gather: one block (128 threads) per target node. Thread d owns
// channels 3d, 3d+1, 3d+2 of the 384-wide filter/message. Wr columns live
// in 60 registers. sin(k*theta) by sincos recurrence (exact freqs = k*pi).
// ---------------------------------------------------------------------------
__global__ __launch_bounds__(128) void node_kernel(
    const float* __restrict__ s_proj, const float* __restrict__ vf,
    const float* __restrict__ pos, const int* __restrict__ src,
    const int* __restrict__ offsets, const int* __restrict__ edge_ord,
    const float* __restrict__ Wr, const float* __restrict__ br,
    float* __restrict__ out, int N) {
  const int n = blockIdx.x;
  if (n >= N) return;
  const int d = threadIdx.x;

  float wr0[NUM_RBF], wr1[NUM_RBF], wr2[NUM_RBF];
#pragma unroll
  for (int r = 0; r < NUM_RBF; ++r) {
    wr0[r] = Wr[r * 384 + 3 * d + 0];
    wr1[r] = Wr[r * 384 + 3 * d + 1];
    wr2[r] = Wr[r * 384 + 3 * d + 2];
  }
  const float br0 = br[3 * d + 0];
  const float br1 = br[3 * d + 1];
  const float br2 = br[3 * d + 2];

  const float px = pos[n * 3 + 0];
  const float py = pos[n * 3 + 1];
  const float pz = pos[n * 3 + 2];

  const int start = offsets[n];
  const int end = offsets[n + 1];

  float accs = 0.f, av0 = 0.f, av1 = 0.f, av2 = 0.f;

  for (int i = start; i < end; ++i) {
    const int e = edge_ord[i];
    const int sn = src[e];
    const float rx = px - pos[sn * 3 + 0];
    const float ry = py - pos[sn * 3 + 1];
    const float rz = pz - pos[sn * 3 + 2];
    const float dist = sqrtf(rx * rx + ry * ry + rz * rz);
    const float inv = 1.0f / dist;
    const float ang = dist * (PI_F / CUT_OFF_F);

    float s1, c1;
    sincosf(ang, &s1, &c1);
    float sk = s1, ck = c1;
    float f0 = br0, f1 = br1, f2 = br2;
#pragma unroll
    for (int r = 0; r < NUM_RBF; ++r) {
      float rb = sk * inv;           // sin((r+1)*ang)/dist
      f0 += rb * wr0[r];
      f1 += rb * wr1[r];
      f2 += rb * wr2[r];
      float sn2 = sk * c1 + ck * s1;
      ck = ck * c1 - sk * s1;
      sk = sn2;
    }
    // cosine cutoff
    f0 = (f0 < CUT_OFF_F) ? 0.5f * (1.0f + cosf(f0 * (PI_F / CUT_OFF_F))) : 0.f;
    f1 = (f1 < CUT_OFF_F) ? 0.5f * (1.0f + cosf(f1 * (PI_F / CUT_OFF_F))) : 0.f;
    f2 = (f2 < CUT_OFF_F) ? 0.5f * (1.0f + cosf(f2 * (PI_F / CUT_OFF_F))) : 0.f;

    const float* srow = s_proj + (size_t)sn * 384 + 3 * d;
    const float m0 = srow[0] * f0;
    const float m1 = srow[1] * f1;
    const float m2 = srow[2] * f2;
    accs += m0;

    const float* vrow = vf + (size_t)sn * 384 + 3 * d;
    av0 += m2 * (rx * inv) + m1 * vrow[0];
    av1 += m2 * (ry * inv) + m1 * vrow[1];
    av2 += m2 * (rz * inv) + m1 * vrow[2];
  }

  out[(size_t)n * 384 + 3 * d + 0] = av0;
  out[(size_t)n * 384 + 3 * d + 1] = av1;
  out[(size_t)n * 384 + 3 * d + 2] = av2;
  out[(size_t)N * 384 + (size_t)n * 128 + d] = accs;
}

// ---------------------------------------------------------------------------
extern "C" void kernel_launch(void* const* d_in, const int* in_sizes, int n_in,
                              void* d_out, int out_size, void* d_ws,
                              size_t ws_size, hipStream_t stream) {
  const float* vf  = (const float*)d_in[0];   // [N,128,3]
  const float* X   = (const float*)d_in[1];   // [N,128]
  const float* pos = (const float*)d_in[2];   // [N,3]
  const int* ei    = (const int*)d_in[3];     // [2,E]
  const float* W1  = (const float*)d_in[4];
  const float* b1  = (const float*)d_in[5];
  const float* W2  = (const float*)d_in[6];
  const float* b2  = (const float*)d_in[7];
  const float* Wr  = (const float*)d_in[8];
  const float* br  = (const float*)d_in[9];

  const int N = in_sizes[1] / D_DIM;
  const int E = in_sizes[3] / 2;
  const int* srcI = ei;
  const int* tgtI = ei + E;
  float* out = (float*)d_out;

  // workspace layout
  char* w = (char*)d_ws;
  float* s_proj = (float*)w;  w += (size_t)N * 384 * sizeof(float);
  int* counts   = (int*)w;    w += (size_t)N * sizeof(int);
  int* offsets  = (int*)w;    w += (size_t)(N + 1) * sizeof(int);
  int* cursor   = (int*)w;    w += (size_t)N * sizeof(int);
  int* chunks   = (int*)w;    w += 64 * sizeof(int);
  int* edge_ord = (int*)w;    w += (size_t)E * sizeof(int);

  const int nch = (N + 1023) / 1024;  // 49 for N=50000 (fits one wave scan)

  zero_kernel<<<(N + 255) / 256, 256, 0, stream>>>(counts, N);
  proj_kernel<<<(N + 31) / 32, 256, 0, stream>>>(X, W1, b1, W2, b2, s_proj, N);
  hist_kernel<<<(E + 255) / 256, 256, 0, stream>>>(tgtI, counts, E);
  chunk_sum_kernel<<<nch, 256, 0, stream>>>(counts, chunks, N);
  scan_chunks_kernel<<<1, 64, 0, stream>>>(chunks, offsets, nch, N, E);
  scan_block_kernel<<<nch, 256, 0, stream>>>(counts, chunks, offsets, cursor, N);
  fill_kernel<<<(E + 255) / 256, 256, 0, stream>>>(tgtI, cursor, edge_ord, E);
  node_kernel<<<N, 128, 0, stream>>>(s_proj, vf, pos, srcI, offsets, edge_ord,
                                     Wr, br, out, N);
}

// Round 2
// 485.045 us; speedup vs baseline: 1.4224x; 1.4224x over previous
//
#include <hip/hip_runtime.h>
#include <math.h>
#include <stddef.h>

#define D_DIM 128
#define NUM_RBF 20
constexpr float PI_F = 3.14159265358979323846f;
constexpr float CUT_OFF_F = 5.0f;
constexpr float SILU_SCALE_F = 1.0f / 0.6f;

// ---------------------------------------------------------------------------
// Fused node projection: s = scaled_silu(X @ W1 + b1) @ W2 + b2   [N, 384]
// (unchanged from R1 — near fp32 vector roofline, not the bottleneck)
// ---------------------------------------------------------------------------
__global__ __launch_bounds__(256) void proj_kernel(
    const float* __restrict__ X, const float* __restrict__ W1,
    const float* __restrict__ b1, const float* __restrict__ W2,
    const float* __restrict__ b2, float* __restrict__ s_out, int N) {
  __shared__ float smA[32 * 128];    // xs then hs
  __shared__ float smB[128 * 128];   // W1 then W2 chunk
  float* xs = smA;
  float* hs = smA;
  float* w1s = smB;
  float* w2c = smB;

  const int t = threadIdx.x;
  const int nb = blockIdx.x * 32;

  {
    const float4* Xv = reinterpret_cast<const float4*>(X);
    float4* xsv = reinterpret_cast<float4*>(xs);
#pragma unroll
    for (int i = 0; i < 4; ++i) {
      int f4 = t + i * 256;
      int node = nb + (f4 >> 5);
      xsv[f4] = (node < N) ? Xv[(size_t)nb * 32 + f4]
                           : make_float4(0.f, 0.f, 0.f, 0.f);
    }
  }
  {
    const float4* W1v = reinterpret_cast<const float4*>(W1);
    float4* wv = reinterpret_cast<float4*>(w1s);
#pragma unroll
    for (int i = 0; i < 16; ++i) wv[t + i * 256] = W1v[t + i * 256];
  }
  __syncthreads();

  const int c0 = (t & 31) * 4;
  const int r0 = (t >> 5) * 4;

  float acc1[4][4] = {};
  for (int k = 0; k < 128; k += 4) {
    float xa[4][4];
#pragma unroll
    for (int i = 0; i < 4; ++i) {
      float4 xt = *reinterpret_cast<const float4*>(&xs[(r0 + i) * 128 + k]);
      xa[i][0] = xt.x; xa[i][1] = xt.y; xa[i][2] = xt.z; xa[i][3] = xt.w;
    }
#pragma unroll
    for (int kk = 0; kk < 4; ++kk) {
      float4 wv = *reinterpret_cast<const float4*>(&w1s[(k + kk) * 128 + c0]);
      float wa[4] = {wv.x, wv.y, wv.z, wv.w};
#pragma unroll
      for (int i = 0; i < 4; ++i)
#pragma unroll
        for (int j = 0; j < 4; ++j) acc1[i][j] += xa[i][kk] * wa[j];
    }
  }
  __syncthreads();

  {
    float b1v[4];
#pragma unroll
    for (int j = 0; j < 4; ++j) b1v[j] = b1[c0 + j];
#pragma unroll
    for (int i = 0; i < 4; ++i) {
#pragma unroll
      for (int j = 0; j < 4; ++j) {
        float h = acc1[i][j] + b1v[j];
        h = h * SILU_SCALE_F / (1.0f + expf(-h));
        hs[(r0 + i) * 128 + c0 + j] = h;
      }
    }
  }

  float acc2[4][3][4];
#pragma unroll
  for (int m = 0; m < 3; ++m)
#pragma unroll
    for (int j = 0; j < 4; ++j) {
      float bv = b2[m * 128 + c0 + j];
#pragma unroll
      for (int i = 0; i < 4; ++i) acc2[i][m][j] = bv;
    }

  for (int kc = 0; kc < 128; kc += 32) {
    __syncthreads();
    {
      const float4* W2v = reinterpret_cast<const float4*>(W2);
      float4* wv = reinterpret_cast<float4*>(w2c);
#pragma unroll
      for (int i = 0; i < 12; ++i)
        wv[t + i * 256] = W2v[(size_t)kc * 96 + t + i * 256];
    }
    __syncthreads();
    for (int kk = 0; kk < 32; ++kk) {
      float xr[4];
#pragma unroll
      for (int i = 0; i < 4; ++i) xr[i] = hs[(r0 + i) * 128 + kc + kk];
#pragma unroll
      for (int m = 0; m < 3; ++m) {
        float4 wv = *reinterpret_cast<const float4*>(&w2c[kk * 384 + m * 128 + c0]);
        float wa[4] = {wv.x, wv.y, wv.z, wv.w};
#pragma unroll
        for (int i = 0; i < 4; ++i)
#pragma unroll
          for (int j = 0; j < 4; ++j) acc2[i][m][j] += xr[i] * wa[j];
      }
    }
  }

#pragma unroll
  for (int i = 0; i < 4; ++i) {
    int node = nb + r0 + i;
    if (node < N) {
#pragma unroll
      for (int m = 0; m < 3; ++m) {
        float4 v = make_float4(acc2[i][m][0], acc2[i][m][1], acc2[i][m][2],
                               acc2[i][m][3]);
        *reinterpret_cast<float4*>(&s_out[(size_t)node * 384 + m * 128 + c0]) = v;
      }
    }
  }
}

// ---------------------------------------------------------------------------
// CSR build (unchanged)
// ---------------------------------------------------------------------------
__global__ void zero_kernel(int* __restrict__ p, int n) {
  int i = blockIdx.x * 256 + threadIdx.x;
  if (i < n) p[i] = 0;
}

__global__ void hist_kernel(const int* __restrict__ tgt, int* __restrict__ counts,
                            int E) {
  int e = blockIdx.x * 256 + threadIdx.x;
  if (e < E) atomicAdd(&counts[tgt[e]], 1);
}

__global__ void chunk_sum_kernel(const int* __restrict__ counts,
                                 int* __restrict__ chunk_sums, int N) {
  __shared__ int red[256];
  int b = blockIdx.x, t = threadIdx.x;
  int base = b * 1024 + t * 4;
  int s = 0;
#pragma unroll
  for (int j = 0; j < 4; ++j) s += (base + j < N) ? counts[base + j] : 0;
  red[t] = s;
  __syncthreads();
  for (int off = 128; off > 0; off >>= 1) {
    if (t < off) red[t] += red[t + off];
    __syncthreads();
  }
  if (t == 0) chunk_sums[b] = red[0];
}

__global__ void scan_chunks_kernel(int* __restrict__ chunk_sums,
                                   int* __restrict__ offsets, int nch, int N,
                                   int E) {
  int t = threadIdx.x;  // one wave; nch <= 64
  int v = (t < nch) ? chunk_sums[t] : 0;
  int orig = v;
#pragma unroll
  for (int off = 1; off < 64; off <<= 1) {
    int y = __shfl_up(v, off);
    if (t >= off) v += y;
  }
  if (t < nch) chunk_sums[t] = v - orig;
  if (t == 0) offsets[N] = E;
}

__global__ void scan_block_kernel(const int* __restrict__ counts,
                                  const int* __restrict__ chunk_off,
                                  int* __restrict__ offsets,
                                  int* __restrict__ cursor, int N) {
  __shared__ int part[256];
  int b = blockIdx.x, t = threadIdx.x;
  int base = b * 1024 + t * 4;
  int v[4];
#pragma unroll
  for (int j = 0; j < 4; ++j) v[j] = (base + j < N) ? counts[base + j] : 0;
  int local = v[0] + v[1] + v[2] + v[3];
  part[t] = local;
  __syncthreads();
  for (int off = 1; off < 256; off <<= 1) {
    int x = 0;
    if (t >= off) x = part[t - off];
    __syncthreads();
    if (t >= off) part[t] += x;
    __syncthreads();
  }
  int run = chunk_off[b] + (part[t] - local);
#pragma unroll
  for (int j = 0; j < 4; ++j) {
    if (base + j < N) {
      offsets[base + j] = run;
      cursor[base + j] = run;
      run += v[j];
    }
  }
}

__global__ void fill_kernel(const int* __restrict__ tgt, int* __restrict__ cursor,
                            int* __restrict__ edge_ord, int E) {
  int e = blockIdx.x * 256 + threadIdx.x;
  if (e < E) {
    int p = atomicAdd(&cursor[tgt[e]], 1);
    edge_ord[p] = e;
  }
}

// ---------------------------------------------------------------------------
// Per-edge geometry: direction + rbf[20], computed ONCE per edge (was
// redundantly recomputed by all 128 lanes of node_kernel in R1).
// ---------------------------------------------------------------------------
__global__ void edge_geom_kernel(const float* __restrict__ pos,
                                 const int* __restrict__ src,
                                 const int* __restrict__ tgt,
                                 float4* __restrict__ dir4,
                                 float* __restrict__ rbuf, int E) {
  int e = blockIdx.x * 256 + threadIdx.x;
  if (e >= E) return;
  const int sn = src[e];
  const int tn = tgt[e];
  const float rx = pos[tn * 3 + 0] - pos[sn * 3 + 0];
  const float ry = pos[tn * 3 + 1] - pos[sn * 3 + 1];
  const float rz = pos[tn * 3 + 2] - pos[sn * 3 + 2];
  const float dist = sqrtf(rx * rx + ry * ry + rz * rz);
  const float inv = 1.0f / dist;
  dir4[e] = make_float4(rx * inv, ry * inv, rz * inv, dist);

  const float ang = dist * (PI_F / CUT_OFF_F);
  float s1, c1;
  sincosf(ang, &s1, &c1);
  float sk = s1, ck = c1;
  float rb[NUM_RBF];
  rb[0] = s1 * inv;
#pragma unroll
  for (int r = 1; r < NUM_RBF; ++r) {
    float sn2 = sk * c1 + ck * s1;
    ck = ck * c1 - sk * s1;
    sk = sn2;
    rb[r] = sk * inv;
  }
  float4* o = reinterpret_cast<float4*>(rbuf + (size_t)e * NUM_RBF);
#pragma unroll
  for (int q = 0; q < 5; ++q)
    o[q] = make_float4(rb[4 * q], rb[4 * q + 1], rb[4 * q + 2], rb[4 * q + 3]);
}

// ---------------------------------------------------------------------------
// Node gather: 128 threads per node, NODES_PER_BLOCK nodes per block (amortize
// the 60-register Wr preamble over ~64 edges instead of ~8). Per edge the
// lanes do only per-channel work: 60 FMA filter dot + cutoff + message.
// Geometry arrives as uniform broadcast float4 loads.
// ---------------------------------------------------------------------------
#define NODES_PER_BLOCK 8

__device__ __forceinline__ float cutoff_f(float x) {
  return (x < CUT_OFF_F) ? 0.5f * (1.0f + __cosf(x * (PI_F / CUT_OFF_F))) : 0.f;
}

__global__ __launch_bounds__(128) void node_kernel(
    const float* __restrict__ s_proj, const float* __restrict__ vf,
    const float4* __restrict__ dir4, const float* __restrict__ rbuf,
    const int* __restrict__ src, const int* __restrict__ offsets,
    const int* __restrict__ edge_ord, const float* __restrict__ Wr,
    const float* __restrict__ br, float* __restrict__ out, int N) {
  const int d = threadIdx.x;

  float wr0[NUM_RBF], wr1[NUM_RBF], wr2[NUM_RBF];
#pragma unroll
  for (int r = 0; r < NUM_RBF; ++r) {
    wr0[r] = Wr[r * 384 + 3 * d + 0];
    wr1[r] = Wr[r * 384 + 3 * d + 1];
    wr2[r] = Wr[r * 384 + 3 * d + 2];
  }
  const float br0 = br[3 * d + 0];
  const float br1 = br[3 * d + 1];
  const float br2 = br[3 * d + 2];

  for (int nn = 0; nn < NODES_PER_BLOCK; ++nn) {
    const int n = blockIdx.x * NODES_PER_BLOCK + nn;
    if (n >= N) break;

    const int start = offsets[n];
    const int end = offsets[n + 1];

    float accs = 0.f, av0 = 0.f, av1 = 0.f, av2 = 0.f;

    for (int i = start; i < end; ++i) {
      const int e = edge_ord[i];
      const int sn = src[e];
      const float4 dir = dir4[e];

      const float4* rbp =
          reinterpret_cast<const float4*>(rbuf + (size_t)e * NUM_RBF);
      float rb[NUM_RBF];
#pragma unroll
      for (int q = 0; q < 5; ++q) {
        float4 v = rbp[q];
        rb[4 * q + 0] = v.x;
        rb[4 * q + 1] = v.y;
        rb[4 * q + 2] = v.z;
        rb[4 * q + 3] = v.w;
      }

      float f0 = br0, f1 = br1, f2 = br2;
#pragma unroll
      for (int r = 0; r < NUM_RBF; ++r) {
        f0 += rb[r] * wr0[r];
        f1 += rb[r] * wr1[r];
        f2 += rb[r] * wr2[r];
      }
      f0 = cutoff_f(f0);
      f1 = cutoff_f(f1);
      f2 = cutoff_f(f2);

      const float* srow = s_proj + (size_t)sn * 384 + 3 * d;
      const float m0 = srow[0] * f0;
      const float m1 = srow[1] * f1;
      const float m2 = srow[2] * f2;
      accs += m0;

      const float* vrow = vf + (size_t)sn * 384 + 3 * d;
      av0 += m2 * dir.x + m1 * vrow[0];
      av1 += m2 * dir.y + m1 * vrow[1];
      av2 += m2 * dir.z + m1 * vrow[2];
    }

    out[(size_t)n * 384 + 3 * d + 0] = av0;
    out[(size_t)n * 384 + 3 * d + 1] = av1;
    out[(size_t)n * 384 + 3 * d + 2] = av2;
    out[(size_t)N * 384 + (size_t)n * 128 + d] = accs;
  }
}

// ---------------------------------------------------------------------------
extern "C" void kernel_launch(void* const* d_in, const int* in_sizes, int n_in,
                              void* d_out, int out_size, void* d_ws,
                              size_t ws_size, hipStream_t stream) {
  const float* vf  = (const float*)d_in[0];   // [N,128,3]
  const float* X   = (const float*)d_in[1];   // [N,128]
  const float* pos = (const float*)d_in[2];   // [N,3]
  const int* ei    = (const int*)d_in[3];     // [2,E] (harness gives int32)
  const float* W1  = (const float*)d_in[4];
  const float* b1  = (const float*)d_in[5];
  const float* W2  = (const float*)d_in[6];
  const float* b2  = (const float*)d_in[7];
  const float* Wr  = (const float*)d_in[8];
  const float* br  = (const float*)d_in[9];

  const int N = in_sizes[1] / D_DIM;
  const int E = in_sizes[3] / 2;
  const int* srcI = ei;
  const int* tgtI = ei + E;
  float* out = (float*)d_out;

  // workspace layout (16B-aligned chunks first)
  char* w = (char*)d_ws;
  float* s_proj = (float*)w;  w += (size_t)N * 384 * sizeof(float);
  float4* dir4  = (float4*)w; w += (size_t)E * sizeof(float4);
  float* rbuf   = (float*)w;  w += (size_t)E * NUM_RBF * sizeof(float);
  int* counts   = (int*)w;    w += (size_t)N * sizeof(int);
  int* offsets  = (int*)w;    w += (size_t)(N + 1) * sizeof(int);
  int* cursor   = (int*)w;    w += (size_t)N * sizeof(int);
  int* chunks   = (int*)w;    w += 64 * sizeof(int);
  int* edge_ord = (int*)w;    w += (size_t)E * sizeof(int);

  const int nch = (N + 1023) / 1024;  // 49 for N=50000

  zero_kernel<<<(N + 255) / 256, 256, 0, stream>>>(counts, N);
  proj_kernel<<<(N + 31) / 32, 256, 0, stream>>>(X, W1, b1, W2, b2, s_proj, N);
  edge_geom_kernel<<<(E + 255) / 256, 256, 0, stream>>>(pos, srcI, tgtI, dir4,
                                                        rbuf, E);
  hist_kernel<<<(E + 255) / 256, 256, 0, stream>>>(tgtI, counts, E);
  chunk_sum_kernel<<<nch, 256, 0, stream>>>(counts, chunks, N);
  scan_chunks_kernel<<<1, 64, 0, stream>>>(chunks, offsets, nch, N, E);
  scan_block_kernel<<<nch, 256, 0, stream>>>(counts, chunks, offsets, cursor, N);
  fill_kernel<<<(E + 255) / 256, 256, 0, stream>>>(tgtI, cursor, edge_ord, E);
  node_kernel<<<(N + NODES_PER_BLOCK - 1) / NODES_PER_BLOCK, 128, 0, stream>>>(
      s_proj, vf, dir4, rbuf, srcI, offsets, edge_ord, Wr, br, out, N);
}

// Round 3
// 390.889 us; speedup vs baseline: 1.7650x; 1.2409x over previous
//
#include <hip/hip_runtime.h>
#include <math.h>
#include <stddef.h>

#define D_DIM 128
#define NUM_RBF 20
constexpr float PI_F = 3.14159265358979323846f;
constexpr float CUT_OFF_F = 5.0f;
constexpr float SILU_SCALE_F = 1.0f / 0.6f;

// ---------------------------------------------------------------------------
// Fused node projection: s = scaled_silu(X @ W1 + b1) @ W2 + b2   [N, 384]
// (unchanged — not the bottleneck)
// ---------------------------------------------------------------------------
__global__ __launch_bounds__(256) void proj_kernel(
    const float* __restrict__ X, const float* __restrict__ W1,
    const float* __restrict__ b1, const float* __restrict__ W2,
    const float* __restrict__ b2, float* __restrict__ s_out, int N) {
  __shared__ float smA[32 * 128];    // xs then hs
  __shared__ float smB[128 * 128];   // W1 then W2 chunk
  float* xs = smA;
  float* hs = smA;
  float* w1s = smB;
  float* w2c = smB;

  const int t = threadIdx.x;
  const int nb = blockIdx.x * 32;

  {
    const float4* Xv = reinterpret_cast<const float4*>(X);
    float4* xsv = reinterpret_cast<float4*>(xs);
#pragma unroll
    for (int i = 0; i < 4; ++i) {
      int f4 = t + i * 256;
      int node = nb + (f4 >> 5);
      xsv[f4] = (node < N) ? Xv[(size_t)nb * 32 + f4]
                           : make_float4(0.f, 0.f, 0.f, 0.f);
    }
  }
  {
    const float4* W1v = reinterpret_cast<const float4*>(W1);
    float4* wv = reinterpret_cast<float4*>(w1s);
#pragma unroll
    for (int i = 0; i < 16; ++i) wv[t + i * 256] = W1v[t + i * 256];
  }
  __syncthreads();

  const int c0 = (t & 31) * 4;
  const int r0 = (t >> 5) * 4;

  float acc1[4][4] = {};
  for (int k = 0; k < 128; k += 4) {
    float xa[4][4];
#pragma unroll
    for (int i = 0; i < 4; ++i) {
      float4 xt = *reinterpret_cast<const float4*>(&xs[(r0 + i) * 128 + k]);
      xa[i][0] = xt.x; xa[i][1] = xt.y; xa[i][2] = xt.z; xa[i][3] = xt.w;
    }
#pragma unroll
    for (int kk = 0; kk < 4; ++kk) {
      float4 wv = *reinterpret_cast<const float4*>(&w1s[(k + kk) * 128 + c0]);
      float wa[4] = {wv.x, wv.y, wv.z, wv.w};
#pragma unroll
      for (int i = 0; i < 4; ++i)
#pragma unroll
        for (int j = 0; j < 4; ++j) acc1[i][j] += xa[i][kk] * wa[j];
    }
  }
  __syncthreads();

  {
    float b1v[4];
#pragma unroll
    for (int j = 0; j < 4; ++j) b1v[j] = b1[c0 + j];
#pragma unroll
    for (int i = 0; i < 4; ++i) {
#pragma unroll
      for (int j = 0; j < 4; ++j) {
        float h = acc1[i][j] + b1v[j];
        h = h * SILU_SCALE_F / (1.0f + expf(-h));
        hs[(r0 + i) * 128 + c0 + j] = h;
      }
    }
  }

  float acc2[4][3][4];
#pragma unroll
  for (int m = 0; m < 3; ++m)
#pragma unroll
    for (int j = 0; j < 4; ++j) {
      float bv = b2[m * 128 + c0 + j];
#pragma unroll
      for (int i = 0; i < 4; ++i) acc2[i][m][j] = bv;
    }

  for (int kc = 0; kc < 128; kc += 32) {
    __syncthreads();
    {
      const float4* W2v = reinterpret_cast<const float4*>(W2);
      float4* wv = reinterpret_cast<float4*>(w2c);
#pragma unroll
      for (int i = 0; i < 12; ++i)
        wv[t + i * 256] = W2v[(size_t)kc * 96 + t + i * 256];
    }
    __syncthreads();
    for (int kk = 0; kk < 32; ++kk) {
      float xr[4];
#pragma unroll
      for (int i = 0; i < 4; ++i) xr[i] = hs[(r0 + i) * 128 + kc + kk];
#pragma unroll
      for (int m = 0; m < 3; ++m) {
        float4 wv = *reinterpret_cast<const float4*>(&w2c[kk * 384 + m * 128 + c0]);
        float wa[4] = {wv.x, wv.y, wv.z, wv.w};
#pragma unroll
        for (int i = 0; i < 4; ++i)
#pragma unroll
          for (int j = 0; j < 4; ++j) acc2[i][m][j] += xr[i] * wa[j];
      }
    }
  }

#pragma unroll
  for (int i = 0; i < 4; ++i) {
    int node = nb + r0 + i;
    if (node < N) {
#pragma unroll
      for (int m = 0; m < 3; ++m) {
        float4 v = make_float4(acc2[i][m][0], acc2[i][m][1], acc2[i][m][2],
                               acc2[i][m][3]);
        *reinterpret_cast<float4*>(&s_out[(size_t)node * 384 + m * 128 + c0]) = v;
      }
    }
  }
}

// ---------------------------------------------------------------------------
// CSR build
// ---------------------------------------------------------------------------
__global__ void zero_kernel(int* __restrict__ p, int n) {
  int i = blockIdx.x * 256 + threadIdx.x;
  if (i < n) p[i] = 0;
}

__global__ void hist_kernel(const int* __restrict__ tgt, int* __restrict__ counts,
                            int E) {
  int e = blockIdx.x * 256 + threadIdx.x;
  if (e < E) atomicAdd(&counts[tgt[e]], 1);
}

__global__ void chunk_sum_kernel(const int* __restrict__ counts,
                                 int* __restrict__ chunk_sums, int N) {
  __shared__ int red[256];
  int b = blockIdx.x, t = threadIdx.x;
  int base = b * 1024 + t * 4;
  int s = 0;
#pragma unroll
  for (int j = 0; j < 4; ++j) s += (base + j < N) ? counts[base + j] : 0;
  red[t] = s;
  __syncthreads();
  for (int off = 128; off > 0; off >>= 1) {
    if (t < off) red[t] += red[t + off];
    __syncthreads();
  }
  if (t == 0) chunk_sums[b] = red[0];
}

__global__ void scan_chunks_kernel(int* __restrict__ chunk_sums,
                                   int* __restrict__ offsets, int nch, int N,
                                   int E) {
  int t = threadIdx.x;  // one wave; nch <= 64
  int v = (t < nch) ? chunk_sums[t] : 0;
  int orig = v;
#pragma unroll
  for (int off = 1; off < 64; off <<= 1) {
    int y = __shfl_up(v, off);
    if (t >= off) v += y;
  }
  if (t < nch) chunk_sums[t] = v - orig;
  if (t == 0) offsets[N] = E;
}

__global__ void scan_block_kernel(const int* __restrict__ counts,
                                  const int* __restrict__ chunk_off,
                                  int* __restrict__ offsets,
                                  int* __restrict__ cursor, int N) {
  __shared__ int part[256];
  int b = blockIdx.x, t = threadIdx.x;
  int base = b * 1024 + t * 4;
  int v[4];
#pragma unroll
  for (int j = 0; j < 4; ++j) v[j] = (base + j < N) ? counts[base + j] : 0;
  int local = v[0] + v[1] + v[2] + v[3];
  part[t] = local;
  __syncthreads();
  for (int off = 1; off < 256; off <<= 1) {
    int x = 0;
    if (t >= off) x = part[t - off];
    __syncthreads();
    if (t >= off) part[t] += x;
    __syncthreads();
  }
  int run = chunk_off[b] + (part[t] - local);
#pragma unroll
  for (int j = 0; j < 4; ++j) {
    if (base + j < N) {
      offsets[base + j] = run;
      cursor[base + j] = run;
      run += v[j];
    }
  }
}

// ---------------------------------------------------------------------------
// Fused edge geometry + CSR scatter: computes dir + rbf[20] once per edge and
// writes them (and src) directly into CSR-sorted slots. Removes the edge_ord
// indirection from node_kernel's dependent-load chain.
// ---------------------------------------------------------------------------
__global__ void edge_geom_kernel(const float* __restrict__ pos,
                                 const int* __restrict__ src,
                                 const int* __restrict__ tgt,
                                 int* __restrict__ cursor,
                                 float4* __restrict__ dir4_s,
                                 float4* __restrict__ rb4_s,
                                 int* __restrict__ src_s, int E) {
  int e = blockIdx.x * 256 + threadIdx.x;
  if (e >= E) return;
  const int sn = src[e];
  const int tn = tgt[e];
  const float rx = pos[tn * 3 + 0] - pos[sn * 3 + 0];
  const float ry = pos[tn * 3 + 1] - pos[sn * 3 + 1];
  const float rz = pos[tn * 3 + 2] - pos[sn * 3 + 2];
  const float dist = sqrtf(rx * rx + ry * ry + rz * rz);
  const float inv = 1.0f / dist;

  const float ang = dist * (PI_F / CUT_OFF_F);
  float s1, c1;
  sincosf(ang, &s1, &c1);
  float sk = s1, ck = c1;
  float rb[NUM_RBF];
  rb[0] = s1 * inv;
#pragma unroll
  for (int r = 1; r < NUM_RBF; ++r) {
    float sn2 = sk * c1 + ck * s1;
    ck = ck * c1 - sk * s1;
    sk = sn2;
    rb[r] = sk * inv;
  }

  const int p = atomicAdd(&cursor[tn], 1);
  dir4_s[p] = make_float4(rx * inv, ry * inv, rz * inv, dist);
  src_s[p] = sn;
  float4* o = rb4_s + (size_t)p * 5;
#pragma unroll
  for (int q = 0; q < 5; ++q)
    o[q] = make_float4(rb[4 * q], rb[4 * q + 1], rb[4 * q + 2], rb[4 * q + 3]);
}

// ---------------------------------------------------------------------------
// Node gather. Per node: lane-parallel coalesced preload of src_s chunk, then
// per-edge sn via __shfl (no dependent global load). dir/rbf loads have
// linear addresses (CSR-sorted arrays). Unroll x2: two edges' loads in
// flight before either compute.
// ---------------------------------------------------------------------------
#define NODES_PER_BLOCK 8

__device__ __forceinline__ float cutoff_f(float x) {
  return (x < CUT_OFF_F) ? 0.5f * (1.0f + __cosf(x * (PI_F / CUT_OFF_F))) : 0.f;
}

struct EdgeData {
  float4 dir;
  float4 rb[5];
  float sx, sy, sz, vx, vy, vz;
};

__device__ __forceinline__ void load_edge(int idx, int sn, int d,
                                          const float* __restrict__ s_proj,
                                          const float* __restrict__ vf,
                                          const float4* __restrict__ dir4_s,
                                          const float4* __restrict__ rb4_s,
                                          EdgeData& ed) {
  ed.dir = dir4_s[idx];
#pragma unroll
  for (int q = 0; q < 5; ++q) ed.rb[q] = rb4_s[(size_t)idx * 5 + q];
  const float* srow = s_proj + (size_t)sn * 384 + 3 * d;
  ed.sx = srow[0]; ed.sy = srow[1]; ed.sz = srow[2];
  const float* vrow = vf + (size_t)sn * 384 + 3 * d;
  ed.vx = vrow[0]; ed.vy = vrow[1]; ed.vz = vrow[2];
}

__global__ __launch_bounds__(128) void node_kernel(
    const float* __restrict__ s_proj, const float* __restrict__ vf,
    const float4* __restrict__ dir4_s, const float4* __restrict__ rb4_s,
    const int* __restrict__ src_s, const int* __restrict__ offsets,
    const float* __restrict__ Wr, const float* __restrict__ br,
    float* __restrict__ out, int N, int E) {
  const int d = threadIdx.x;
  const int lane = d & 63;

  float wr0[NUM_RBF], wr1[NUM_RBF], wr2[NUM_RBF];
#pragma unroll
  for (int r = 0; r < NUM_RBF; ++r) {
    wr0[r] = Wr[r * 384 + 3 * d + 0];
    wr1[r] = Wr[r * 384 + 3 * d + 1];
    wr2[r] = Wr[r * 384 + 3 * d + 2];
  }
  const float br0 = br[3 * d + 0];
  const float br1 = br[3 * d + 1];
  const float br2 = br[3 * d + 2];

  for (int nn = 0; nn < NODES_PER_BLOCK; ++nn) {
    const int n = blockIdx.x * NODES_PER_BLOCK + nn;
    if (n >= N) break;

    const int start = offsets[n];
    const int end = offsets[n + 1];

    float accs = 0.f, av0 = 0.f, av1 = 0.f, av2 = 0.f;

    for (int base = start; base < end; base += 64) {
      const int m = min(64, end - base);
      // coalesced metadata preload (both waves hold identical copies)
      int ld = base + lane;
      if (ld >= E) ld = E - 1;
      const int sn_l = src_s[ld];

      int i = 0;
      for (; i + 2 <= m; i += 2) {
        const int sn0 = __shfl(sn_l, i);
        const int sn1 = __shfl(sn_l, i + 1);
        EdgeData e0, e1;
        load_edge(base + i, sn0, d, s_proj, vf, dir4_s, rb4_s, e0);
        load_edge(base + i + 1, sn1, d, s_proj, vf, dir4_s, rb4_s, e1);

#pragma unroll
        for (int u = 0; u < 2; ++u) {
          const EdgeData& ed = (u == 0) ? e0 : e1;
          const float* rbf = reinterpret_cast<const float*>(&ed.rb[0]);
          float f0 = br0, f1 = br1, f2 = br2;
#pragma unroll
          for (int r = 0; r < NUM_RBF; ++r) {
            f0 += rbf[r] * wr0[r];
            f1 += rbf[r] * wr1[r];
            f2 += rbf[r] * wr2[r];
          }
          f0 = cutoff_f(f0);
          f1 = cutoff_f(f1);
          f2 = cutoff_f(f2);
          const float m0 = ed.sx * f0;
          const float m1 = ed.sy * f1;
          const float m2 = ed.sz * f2;
          accs += m0;
          av0 += m2 * ed.dir.x + m1 * ed.vx;
          av1 += m2 * ed.dir.y + m1 * ed.vy;
          av2 += m2 * ed.dir.z + m1 * ed.vz;
        }
      }
      if (i < m) {
        const int sn0 = __shfl(sn_l, i);
        EdgeData e0;
        load_edge(base + i, sn0, d, s_proj, vf, dir4_s, rb4_s, e0);
        const float* rbf = reinterpret_cast<const float*>(&e0.rb[0]);
        float f0 = br0, f1 = br1, f2 = br2;
#pragma unroll
        for (int r = 0; r < NUM_RBF; ++r) {
          f0 += rbf[r] * wr0[r];
          f1 += rbf[r] * wr1[r];
          f2 += rbf[r] * wr2[r];
        }
        f0 = cutoff_f(f0);
        f1 = cutoff_f(f1);
        f2 = cutoff_f(f2);
        const float m0 = e0.sx * f0;
        const float m1 = e0.sy * f1;
        const float m2 = e0.sz * f2;
        accs += m0;
        av0 += m2 * e0.dir.x + m1 * e0.vx;
        av1 += m2 * e0.dir.y + m1 * e0.vy;
        av2 += m2 * e0.dir.z + m1 * e0.vz;
      }
    }

    out[(size_t)n * 384 + 3 * d + 0] = av0;
    out[(size_t)n * 384 + 3 * d + 1] = av1;
    out[(size_t)n * 384 + 3 * d + 2] = av2;
    out[(size_t)N * 384 + (size_t)n * 128 + d] = accs;
  }
}

// ---------------------------------------------------------------------------
extern "C" void kernel_launch(void* const* d_in, const int* in_sizes, int n_in,
                              void* d_out, int out_size, void* d_ws,
                              size_t ws_size, hipStream_t stream) {
  const float* vf  = (const float*)d_in[0];   // [N,128,3]
  const float* X   = (const float*)d_in[1];   // [N,128]
  const float* pos = (const float*)d_in[2];   // [N,3]
  const int* ei    = (const int*)d_in[3];     // [2,E]
  const float* W1  = (const float*)d_in[4];
  const float* b1  = (const float*)d_in[5];
  const float* W2  = (const float*)d_in[6];
  const float* b2  = (const float*)d_in[7];
  const float* Wr  = (const float*)d_in[8];
  const float* br  = (const float*)d_in[9];

  const int N = in_sizes[1] / D_DIM;
  const int E = in_sizes[3] / 2;
  const int* srcI = ei;
  const int* tgtI = ei + E;
  float* out = (float*)d_out;

  // workspace layout (16B-aligned chunks first)
  char* w = (char*)d_ws;
  float* s_proj  = (float*)w;  w += (size_t)N * 384 * sizeof(float);
  float4* dir4_s = (float4*)w; w += (size_t)E * sizeof(float4);
  float4* rb4_s  = (float4*)w; w += (size_t)E * 5 * sizeof(float4);
  int* src_s     = (int*)w;    w += (size_t)E * sizeof(int);
  int* counts    = (int*)w;    w += (size_t)N * sizeof(int);
  int* offsets   = (int*)w;    w += (size_t)(N + 1) * sizeof(int);
  int* cursor    = (int*)w;    w += (size_t)N * sizeof(int);
  int* chunks    = (int*)w;    w += 64 * sizeof(int);

  const int nch = (N + 1023) / 1024;  // 49 for N=50000

  zero_kernel<<<(N + 255) / 256, 256, 0, stream>>>(counts, N);
  proj_kernel<<<(N + 31) / 32, 256, 0, stream>>>(X, W1, b1, W2, b2, s_proj, N);
  hist_kernel<<<(E + 255) / 256, 256, 0, stream>>>(tgtI, counts, E);
  chunk_sum_kernel<<<nch, 256, 0, stream>>>(counts, chunks, N);
  scan_chunks_kernel<<<1, 64, 0, stream>>>(chunks, offsets, nch, N, E);
  scan_block_kernel<<<nch, 256, 0, stream>>>(counts, chunks, offsets, cursor, N);
  edge_geom_kernel<<<(E + 255) / 256, 256, 0, stream>>>(pos, srcI, tgtI, cursor,
                                                        dir4_s, rb4_s, src_s, E);
  node_kernel<<<(N + NODES_PER_BLOCK - 1) / NODES_PER_BLOCK, 128, 0, stream>>>(
      s_proj, vf, dir4_s, rb4_s, src_s, offsets, Wr, br, out, N, E);
}